// Round 12
// baseline (46.263 us; speedup 1.0000x reference)
//
#include <hip/hip_runtime.h>
#include <math.h>

#define NROWS 1546
#define INDIM 1546
#define ODIM  64
#define NDRUG 1373
#define MINN  1e-15f
#define MAXNRM 0.996f   // (1 - 4e-3)/sqrt(c), c=1

#define QSTR 256        // packed quad stride: idx = (k>>2)*QSTR + col*4 + (k&3)
#define NQ   387        // ceil(1546/4)
#define NQF  386        // full quads (k < 1544); tail k = 1544,1545
#define XSTR 1552       // LDS row stride (floats); 1552*4 % 16 == 0
#define NBLK 194        // row-groups of 8
#define NWAV 16         // waves per block (1024 threads)

__device__ __forceinline__ float artanh_(float x) {
    x = fminf(fmaxf(x, -1.0f + 1e-7f), 1.0f - 1e-7f);
    return 0.5f * (log1pf(x) - log1pf(-x));
}

__device__ __forceinline__ float wsum(float v) {
#pragma unroll
    for (int off = 32; off > 0; off >>= 1) v += __shfl_xor(v, off, 64);
    return v;
}

// ---- kernel 1: W[64][1546] -> packed Wq (both matrices) ----
__global__ void prep_kernel(const float* __restrict__ Wd, const float* __restrict__ Wm,
                            float* __restrict__ WqD, float* __restrict__ WqM) {
    int total = ODIM * INDIM;
    for (int i = blockIdx.x * blockDim.x + threadIdx.x; i < total; i += gridDim.x * blockDim.x) {
        int o = i / INDIM;
        int k = i - o * INDIM;
        int qi = (k >> 2) * QSTR + o * 4 + (k & 3);
        WqD[qi] = Wd[i];
        WqM[qi] = Wm[i];
    }
}

// ---- kernel 2: full-K x@W^T + hyperbolic epilogue fused (8 rows/block, 16 waves) ----
__global__ __launch_bounds__(1024) void liner_full(
    const float* __restrict__ X, const float* __restrict__ WqD, const float* __restrict__ WqM,
    const float* __restrict__ bd, const float* __restrict__ bm,
    float* __restrict__ liner, float* __restrict__ xtq) {
    __shared__ __align__(16) float xs[8 * XSTR];
    __shared__ float red[NWAV][8][64];
    __shared__ float ssp[2][8];
    __shared__ float hbs[2][64];
    __shared__ float hb2s[2];
    int tid = threadIdx.x, wave = tid >> 6, lane = tid & 63;
    int row0 = blockIdx.x * 8;

    {   // stage: wave w handles row (w&7), half (w>>3); fused partial row norms
        int r = wave & 7, half = wave >> 3;
        int gr = min(row0 + r, NROWS - 1);
        int nf2 = half ? 385 : 388;           // 776 + 770 = 1546 floats
        const float2* src = (const float2*)(X + (size_t)gr * INDIM) + half * 388;
        float2* dst = (float2*)(xs + r * XSTR) + half * 388;
        float ss = 0.f;
        for (int c = lane; c < nf2; c += 64) {
            float2 v = src[c];
            dst[c] = v;
            ss = fmaf(v.x, v.x, fmaf(v.y, v.y, ss));
        }
        ss = wsum(ss);
        if (lane == 0) ssp[half][r] = ss;
    }
    __syncthreads();

    if (wave < 2) {   // hyp_bias = proj(expmap0(bias)): wave0 drug, wave1 micr
        const float* b = wave ? bm : bd;
        float v = b[lane];
        float un2 = wsum(v * v);
        float un = fmaxf(sqrtf(un2), MINN);
        float e = tanhf(un) * v / un;
        float en2 = wsum(e * e);
        float en = fmaxf(sqrtf(en2), MINN);
        float scl = (en > MAXNRM) ? (MAXNRM / en) : 1.0f;
        hbs[wave][lane] = e * scl;
        if (lane == 0) hb2s[wave] = en2 * scl * scl;
    }

    float acc[8];
#pragma unroll
    for (int r = 0; r < 8; ++r) acc[r] = 0.f;

    int qoff = lane * 4;
    bool uni = (row0 + 7 < NDRUG) || (row0 >= NDRUG);
    if (uni) {
        const float* wq = ((row0 < NDRUG) ? WqD : WqM) + qoff;
#pragma unroll 2
        for (int q = wave; q < NQF; q += NWAV) {   // wave-strided quad subset
            float4 w = *(const float4*)(wq + (size_t)q * QSTR);
#pragma unroll
            for (int r = 0; r < 8; ++r) {          // wave-uniform LDS broadcast
                float4 a = *(const float4*)(xs + r * XSTR + 4 * q);
                acc[r] = fmaf(a.x, w.x, acc[r]); acc[r] = fmaf(a.y, w.y, acc[r]);
                acc[r] = fmaf(a.z, w.z, acc[r]); acc[r] = fmaf(a.w, w.w, acc[r]);
            }
        }
    } else {
        // single boundary row-group (rows straddle 1373): load both, select per row
        const float* wqd = WqD + qoff;
        const float* wqm = WqM + qoff;
        for (int q = wave; q < NQF; q += NWAV) {
            float4 wd = *(const float4*)(wqd + (size_t)q * QSTR);
            float4 wm = *(const float4*)(wqm + (size_t)q * QSTR);
#pragma unroll
            for (int r = 0; r < 8; ++r) {
                bool dd = (row0 + r) < NDRUG;
                float4 w;
                w.x = dd ? wd.x : wm.x; w.y = dd ? wd.y : wm.y;
                w.z = dd ? wd.z : wm.z; w.w = dd ? wd.w : wm.w;
                float4 a = *(const float4*)(xs + r * XSTR + 4 * q);
                acc[r] = fmaf(a.x, w.x, acc[r]); acc[r] = fmaf(a.y, w.y, acc[r]);
                acc[r] = fmaf(a.z, w.z, acc[r]); acc[r] = fmaf(a.w, w.w, acc[r]);
            }
        }
    }
    if (wave == 0) {   // scalar K tail: k = 1544,1545
        for (int k = NQF * 4; k < INDIM; ++k) {
            float wdv = WqD[(size_t)(k >> 2) * QSTR + lane * 4 + (k & 3)];
            float wmv = WqM[(size_t)(k >> 2) * QSTR + lane * 4 + (k & 3)];
#pragma unroll
            for (int r = 0; r < 8; ++r) {
                float w = (row0 + r < NDRUG) ? wdv : wmv;
                acc[r] = fmaf(xs[r * XSTR + k], w, acc[r]);
            }
        }
    }

#pragma unroll
    for (int r = 0; r < 8; ++r) red[wave][r][lane] = acc[r];
    __syncthreads();

    if (wave < 8) {   // epilogue: one wave per row
        int r = wave;
        int grow = row0 + r;
        if (grow < NROWS) {
            float mx = 0.f;
#pragma unroll
            for (int w = 0; w < NWAV; ++w) mx += red[w][r][lane];
            float xn2 = ssp[0][r] + ssp[1][r];
            float mxn2 = wsum(mx * mx);
            float xn = fmaxf(sqrtf(xn2), MINN);
            float mxn = fmaxf(sqrtf(mxn2), MINN);
            float g = mxn / xn * artanh_(xn);
            float t = tanhf(g);
            float res = t * mx / mxn;          // |res| == |t|
            float rn = fabsf(t);
            if (rn > MAXNRM) { res *= MAXNRM / rn; rn = MAXNRM; }
            int mi = (grow < NDRUG) ? 0 : 1;
            float y = hbs[mi][lane];
            float y2 = hb2s[mi];
            float x2 = rn * rn;
            float xy = wsum(res * y);
            float num = (1.0f + 2.0f * xy + y2) * res + (1.0f - x2) * y;
            float den = 1.0f + 2.0f * xy + x2 * y2;
            float v = num / fmaxf(den, MINN);
            float v2 = wsum(v * v);
            float vn = fmaxf(sqrtf(v2), MINN);
            if (vn > MAXNRM) { v *= MAXNRM / vn; vn = MAXNRM; }
            float xt = artanh_(vn) / vn * v;   // logmap0
            liner[(size_t)grow * ODIM + lane] = v;
            xtq[(size_t)(grow >> 2) * QSTR + lane * 4 + (grow & 3)] = xt;
        }
    }
}

// ---- kernel 3: full-K adj@xtan + expmap0/proj + gated HypAct fused (+adj copy) ----
__global__ __launch_bounds__(1024) void agg_full(
    const float* __restrict__ ADJ, const float* __restrict__ xtq,
    const float* __restrict__ liner, const float* __restrict__ WN /*[128][64]*/,
    const float* __restrict__ biasnode, float* __restrict__ out_h,
    float* __restrict__ adj_out) {
    __shared__ __align__(16) float xs[8 * XSTR];
    __shared__ float red[NWAV][8][64];
    __shared__ float zl[8][128];
    int tid = threadIdx.x, wave = tid >> 6, lane = tid & 63;
    int row0 = blockIdx.x * 8;

    {   // stage adj rows + fused copy to second tuple output
        int r = wave & 7, half = wave >> 3;
        int gr0 = row0 + r;
        int gr = min(gr0, NROWS - 1);
        int nf2 = half ? 385 : 388;
        const float2* src = (const float2*)(ADJ + (size_t)gr * INDIM) + half * 388;
        float2* dst = (float2*)(xs + r * XSTR) + half * 388;
        if (gr0 < NROWS) {
            float2* cp = (float2*)(adj_out + (size_t)gr0 * INDIM) + half * 388;
            for (int c = lane; c < nf2; c += 64) { float2 v = src[c]; dst[c] = v; cp[c] = v; }
        } else {
            for (int c = lane; c < nf2; c += 64) dst[c] = src[c];
        }
    }
    __syncthreads();

    float acc[8];
#pragma unroll
    for (int r = 0; r < 8; ++r) acc[r] = 0.f;

    const float* wq = xtq + lane * 4;
#pragma unroll 2
    for (int q = wave; q < NQF; q += NWAV) {
        float4 w = *(const float4*)(wq + (size_t)q * QSTR);
#pragma unroll
        for (int r = 0; r < 8; ++r) {
            float4 a = *(const float4*)(xs + r * XSTR + 4 * q);
            acc[r] = fmaf(a.x, w.x, acc[r]); acc[r] = fmaf(a.y, w.y, acc[r]);
            acc[r] = fmaf(a.z, w.z, acc[r]); acc[r] = fmaf(a.w, w.w, acc[r]);
        }
    }
    if (wave == 0) {   // scalar K tail: k = 1544,1545
        for (int k = NQF * 4; k < INDIM; ++k) {
            float w = xtq[(size_t)(k >> 2) * QSTR + lane * 4 + (k & 3)];
#pragma unroll
            for (int r = 0; r < 8; ++r) acc[r] = fmaf(xs[r * XSTR + k], w, acc[r]);
        }
    }

#pragma unroll
    for (int r = 0; r < 8; ++r) red[wave][r][lane] = acc[r];
    __syncthreads();

    if (wave < 8) {   // epilogue: one wave per row (HypAct)
        int r = wave;
        int grow = row0 + r;
        if (grow < NROWS) {
            float s = 0.f;
#pragma unroll
            for (int w = 0; w < NWAV; ++w) s += red[w][r][lane];
            float sn2 = wsum(s * s);
            float sn = fmaxf(sqrtf(sn2), MINN);
            float th = tanhf(sn);
            float agg = th * s / sn;           // expmap0; |agg| == th
            if (th > MAXNRM) agg *= MAXNRM / th;
            float lin = liner[(size_t)grow * ODIM + lane];
            zl[r][lane] = agg;
            zl[r][64 + lane] = lin;            // same-wave LDS RAW, no barrier needed
            float d = biasnode[grow];
            const float* w = WN + lane;
#pragma unroll 8
            for (int f = 0; f < 128; ++f) d = fmaf(zl[r][f], w[f * 64], d);
            d = fmaxf(d, 0.0f);
            out_h[(size_t)grow * ODIM + lane] = d * agg + (1.0f - d) * lin;
        }
    }
}

extern "C" void kernel_launch(void* const* d_in, const int* in_sizes, int n_in,
                              void* d_out, int out_size, void* d_ws, size_t ws_size,
                              hipStream_t stream) {
    const float* x   = (const float*)d_in[0];
    const float* adj = (const float*)d_in[1];
    const float* Wd  = (const float*)d_in[2];
    const float* Wm  = (const float*)d_in[3];
    const float* bd  = (const float*)d_in[4];
    const float* bm  = (const float*)d_in[5];
    const float* wn  = (const float*)d_in[6];
    const float* bn  = (const float*)d_in[7];
    float* out = (float*)d_out;
    float* ws  = (float*)d_ws;

    const int WELEMS = ODIM * INDIM;          // 98944
    const int QELEMS = NQ * QSTR;             // 99072
    float* WqD   = ws;                        // 99072
    float* WqM   = WqD + QELEMS;              // 99072
    float* liner = WqM + QELEMS;              // 98944
    float* xtq   = liner + WELEMS;            // 99072 (packed)
    // total ws use: ~1.59 MB

    prep_kernel<<<256, 256, 0, stream>>>(Wd, Wm, WqD, WqM);
    liner_full<<<NBLK, 1024, 0, stream>>>(x, WqD, WqM, bd, bm, liner, xtq);
    agg_full<<<NBLK, 1024, 0, stream>>>(adj, xtq, liner, wn, bn, out,
                                        out + WELEMS);
}